// Round 13
// baseline (456.112 us; speedup 1.0000x reference)
//
#include <hip/hip_runtime.h>

#define Bc 16
#define Tc 16
#define Cc 512
#define Kc 64
#define Sc 196
#define KS (Kc*Sc)          // 12544
#define BKS (Bc*Kc*Sc)      // 200704
#define TBKS (Tc*BKS)       // 3211264
#define GFIN (16*64*512)    // 524288
#define PART_N (8*GFIN)     // 4194304
#define PX 256              // 16 rows * 16 cols per plane
#define PLB2 (Kc*PX)        // 16384 elems per b

typedef __attribute__((ext_vector_type(8))) short bf16x8;
typedef __attribute__((ext_vector_type(4))) float f32x4;

__device__ __forceinline__ float sigmoid_f(float x) { return 1.f / (1.f + __expf(-x)); }
__device__ __forceinline__ float tanh_f(float x) { return 1.f - 2.f / (__expf(2.f * x) + 1.f); }

__device__ __forceinline__ float b2f(unsigned short u) {
    return __uint_as_float(((unsigned)u) << 16);
}
__device__ __forceinline__ unsigned short f2b(float f) {   // RNE
    unsigned u = __float_as_uint(f);
    return (unsigned short)((u + 0x7FFFu + ((u >> 16) & 1u)) >> 16);
}
// split f = hi + lo (hi = truncated-mantissa bf16; lo = residual)
__device__ __forceinline__ void split1(float f, unsigned short& h, unsigned short& l) {
    unsigned u = __float_as_uint(f);
    unsigned uh = u & 0xffff0000u;
    h = (unsigned short)(uh >> 16);
    float fl = f - __uint_as_float(uh);
    l = (unsigned short)(__float_as_uint(fl) >> 16);
}

// neighbor-lane reads within 16-lane DPP rows; out-of-range -> 0 (bound_ctrl)
__device__ __forceinline__ float dpp_prev(float v) {
    return __int_as_float(__builtin_amdgcn_mov_dpp(__float_as_int(v), 0x111, 0xf, 0xf, true));
}
__device__ __forceinline__ float dpp_next(float v) {
    return __int_as_float(__builtin_amdgcn_mov_dpp(__float_as_int(v), 0x101, 0xf, 0xf, true));
}

// ---------------- prep W: split share_w [64][512] into bf16 hi/lo ----------------
__global__ __launch_bounds__(256) void k_prep_w(const float* __restrict__ w,
        unsigned short* __restrict__ wh, unsigned short* __restrict__ wl) {
    int idx = blockIdx.x * 256 + threadIdx.x;   // 32768 total
    unsigned short h, l;
    split1(w[idx], h, l);
    wh[idx] = h; wl[idx] = l;
}

// ---------------- zero-init planes (pads must be 0; interiors overwritten) ----------------
__global__ __launch_bounds__(256) void k_init(float4* __restrict__ h32,
        float4* __restrict__ h16, float4* __restrict__ rh16) {
    const int i = blockIdx.x * 256 + threadIdx.x;   // grid 256 -> 65536 threads
    const float4 z = make_float4(0.f, 0.f, 0.f, 0.f);
    h32[i] = z;                                      // 262144 floats
    if (i < 32768) { h16[i] = z; rh16[i] = z; }      // 262144 ushorts each
}

// ---------------- conv1x1 via MFMA: D[gs][k] = X^T * W^T, bf16x3; t0 fused ----------------
// grid 784 (64 gs), 512 thr = 8 waves: wave = (mt = w&3 gs-tile) x (np = w>>2 k-pair)
__global__ __launch_bounds__(512) void k_conv1x1(const float* __restrict__ x,
        const unsigned short* __restrict__ wh, const unsigned short* __restrict__ wl,
        const float* __restrict__ bias, float* __restrict__ wxb,
        float* __restrict__ assign0, float* __restrict__ hplane32,
        unsigned short* __restrict__ hplane16) {
    __shared__ unsigned short Xh[64 * 40];
    __shared__ unsigned short Xl[64 * 40];
    const int gs0 = blockIdx.x * 64;
    const int tid = threadIdx.x;
    const int wv = tid >> 6, lane = tid & 63;
    const int lg = lane >> 4, ln = lane & 15;
    const int mt = wv & 3, np = wv >> 2;
    // staging: thread = (gsl = tid&63 fastest -> coalesced, c4 = (tid>>6)*4)
    const int gslS = tid & 63;
    const int c4S = (tid >> 6) * 4;
    const int gsS = gs0 + gslS;
    const int nS = gsS / Sc, sS = gsS - nS * Sc;
    const float* xcol = x + (size_t)nS * (Cc * Sc) + sS;
    const int colS = (((c4S >> 3) ^ ((gslS >> 3) & 3)) << 3) + (c4S & 7);  // swizzled col
    const int kA = np * 32 + ln;
    const float bias0 = bias[kA], bias1 = bias[kA + 16];
    const int gsA = mt * 16 + ln;
    const int swzA = (gsA >> 3) & 3;

    float xr[4];
#pragma unroll
    for (int i = 0; i < 4; ++i) xr[i] = xcol[(size_t)(c4S + i) * Sc];

    f32x4 acc0 = {0.f, 0.f, 0.f, 0.f}, acc1 = {0.f, 0.f, 0.f, 0.f};
    for (int c0 = 0; c0 < Cc; c0 += 32) {
        __syncthreads();
        {
            ushort4 h, l;
            split1(xr[0], h.x, l.x); split1(xr[1], h.y, l.y);
            split1(xr[2], h.z, l.z); split1(xr[3], h.w, l.w);
            *(ushort4*)(Xh + gslS * 40 + colS) = h;
            *(ushort4*)(Xl + gslS * 40 + colS) = l;
        }
        __syncthreads();
        if (c0 + 32 < Cc) {
#pragma unroll
            for (int i = 0; i < 4; ++i) xr[i] = xcol[(size_t)(c0 + 32 + c4S + i) * Sc];
        }
        bf16x8 B0h = *(const bf16x8*)(wh + (size_t)kA * Cc + c0 + lg * 8);
        bf16x8 B0l = *(const bf16x8*)(wl + (size_t)kA * Cc + c0 + lg * 8);
        bf16x8 B1h = *(const bf16x8*)(wh + (size_t)(kA + 16) * Cc + c0 + lg * 8);
        bf16x8 B1l = *(const bf16x8*)(wl + (size_t)(kA + 16) * Cc + c0 + lg * 8);
        bf16x8 Af = *(const bf16x8*)(Xh + gsA * 40 + ((lg ^ swzA) << 3));
        bf16x8 Alo = *(const bf16x8*)(Xl + gsA * 40 + ((lg ^ swzA) << 3));
        acc0 = __builtin_amdgcn_mfma_f32_16x16x32_bf16(Af, B0h, acc0, 0, 0, 0);
        acc0 = __builtin_amdgcn_mfma_f32_16x16x32_bf16(Alo, B0h, acc0, 0, 0, 0);
        acc0 = __builtin_amdgcn_mfma_f32_16x16x32_bf16(Af, B0l, acc0, 0, 0, 0);
        acc1 = __builtin_amdgcn_mfma_f32_16x16x32_bf16(Af, B1h, acc1, 0, 0, 0);
        acc1 = __builtin_amdgcn_mfma_f32_16x16x32_bf16(Alo, B1h, acc1, 0, 0, 0);
        acc1 = __builtin_amdgcn_mfma_f32_16x16x32_bf16(Af, B1l, acc1, 0, 0, 0);
    }
#pragma unroll
    for (int r = 0; r < 4; ++r) {
        const int gs = gs0 + mt * 16 + lg * 4 + r;
        const int n = gs / Sc, s = gs - (gs / Sc) * Sc;
        const int t = n & 15, bb = n >> 4;
        const float v0 = acc0[r] + bias0;
        const float v1 = acc1[r] + bias1;
        const size_t rowbase = ((size_t)t * Bc + bb) * Kc;
        wxb[(rowbase + kA) * Sc + s] = v0;
        wxb[(rowbase + kA + 16) * Sc + s] = v1;
        if (t == 0) {   // fused GRU t=0: h = (1-sig(p))*tanh(p)
            const int px = (s / 14 + 1) * 16 + (s - (s / 14) * 14 + 1);
            const float a0 = (1.f - sigmoid_f(v0)) * tanh_f(v0);
            const float a1 = (1.f - sigmoid_f(v1)) * tanh_f(v1);
            assign0[((size_t)bb * Kc + kA) * Sc + s] = a0;
            assign0[((size_t)bb * Kc + kA + 16) * Sc + s] = a1;
            const size_t pp0 = (size_t)bb * PLB2 + (size_t)kA * PX + px;
            const size_t pp1 = (size_t)bb * PLB2 + (size_t)(kA + 16) * PX + px;
            hplane32[pp0] = a0; hplane16[pp0] = f2b(a0);
            hplane32[pp1] = a1; hplane16[pp1] = f2b(a1);
        }
    }
}

// ---------------- GRU gates: grid (16 b, 16 kt), 512 thr = 8 waves = (kp 2) x (kiq 4) ----------------
__global__ __launch_bounds__(512) void k_gru_gates(const unsigned short* __restrict__ hplane16,
        const float* __restrict__ wxb_t, const float* __restrict__ Uz, const float* __restrict__ Ur,
        float* __restrict__ zb, unsigned short* __restrict__ rhplane16) {
    extern __shared__ float lds[];
    unsigned short* P = (unsigned short*)lds;   // [64][256] bf16
    float* red = lds + 8192;
    const int b = blockIdx.x;
    const int k0 = blockIdx.y * 4;
    const int tid = threadIdx.x;
    const int wv = __builtin_amdgcn_readfirstlane(tid >> 6);
    const int lane = tid & 63;
    const int kp = wv >> 2, kiq = wv & 3;

    float preE[4]; bool valE[4]; size_t csE[4]; int kEa[4];
#pragma unroll
    for (int q = 0; q < 4; ++q) {
        const int o = tid + q * 512;
        const int set = o >> 8, px = o & 255;
        const int kp_o = set >> 2, r = set & 1;
        kEa[q] = k0 + kp_o * 2 + r;
        const int row = px >> 4, col = px & 15;
        valE[q] = (row >= 1 && row <= 14 && col >= 1 && col <= 14);
        csE[q] = ((size_t)b * Kc + kEa[q]) * Sc + (valE[q] ? (row - 1) * 14 + (col - 1) : 0);
        preE[q] = valE[q] ? wxb_t[csE[q]] : 0.f;
    }
    {
        const float4* src = (const float4*)(hplane16 + (size_t)b * PLB2);
        float4* dst = (float4*)P;
#pragma unroll
        for (int it = 0; it < 4; ++it) dst[it * 512 + tid] = src[it * 512 + tid];
    }
    __syncthreads();

    const int yp = lane >> 2, xq = (lane & 3) << 2;
    const int rowbase = (yp > 0) ? (yp - 1) : 0;
    const float* uz0 = Uz + (size_t)(k0 + kp * 2) * 576 + kiq * 144;
    const float* ur0 = Ur + (size_t)(k0 + kp * 2) * 576 + kiq * 144;
    float az[2][4] = {}, ar[2][4] = {};
    const unsigned short* Pw = P + (size_t)(kiq * 16) * PX + rowbase * 16 + xq;
#pragma unroll 2
    for (int ki = 0; ki < 16; ++ki) {
        const unsigned short* pk = Pw + ki * PX;
#pragma unroll
        for (int dy = 0; dy < 3; ++dy) {
            ushort4 u = *(const ushort4*)(pk + dy * 16);
            float4 m = make_float4(b2f(u.x), b2f(u.y), b2f(u.z), b2f(u.w));
            float e0 = dpp_prev(m.w);
            float e4 = dpp_next(m.x);
#pragma unroll
            for (int r = 0; r < 2; ++r) {
                const float* wz = uz0 + r * 576 + ki * 9 + dy * 3;
                float c0 = wz[0], c1 = wz[1], c2 = wz[2];
                az[r][0] += c0*e0  + c1*m.x + c2*m.y;
                az[r][1] += c0*m.x + c1*m.y + c2*m.z;
                az[r][2] += c0*m.y + c1*m.z + c2*m.w;
                az[r][3] += c0*m.z + c1*m.w + c2*e4;
                const float* wr = ur0 + r * 576 + ki * 9 + dy * 3;
                float d0 = wr[0], d1 = wr[1], d2 = wr[2];
                ar[r][0] += d0*e0  + d1*m.x + d2*m.y;
                ar[r][1] += d0*m.x + d1*m.y + d2*m.z;
                ar[r][2] += d0*m.y + d1*m.z + d2*m.w;
                ar[r][3] += d0*m.z + d1*m.w + d2*e4;
            }
        }
    }
    {
        float* rp = red + (size_t)wv * 1024 + lane;
#pragma unroll
        for (int r = 0; r < 2; ++r)
#pragma unroll
            for (int jj = 0; jj < 4; ++jj) {
                rp[(size_t)(r * 4 + jj) * 64] = az[r][jj];
                rp[(size_t)(8 + r * 4 + jj) * 64] = ar[r][jj];
            }
    }
    __syncthreads();
#pragma unroll
    for (int q = 0; q < 4; ++q) {
        const int o = tid + q * 512;
        const int set = o >> 8, px = o & 255;
        const int kp_o = set >> 2, g = (set >> 1) & 1, r = set & 1;
        const int lane_r = ((px >> 4) << 2) + ((px & 15) >> 2);
        const int v = (g * 2 + r) * 4 + (px & 3);
        float s0 = 0.f;
#pragma unroll
        for (int kq2 = 0; kq2 < 4; ++kq2)
            s0 += red[(size_t)((kp_o * 4 + kq2) * 16 + v) * 64 + lane_r];
        if (valE[q]) {
            float sv = sigmoid_f(preE[q] + s0);
            if (g == 0) {
                zb[csE[q]] = sv;
            } else {
                float hv = b2f(P[(size_t)kEa[q] * PX + px]);
                rhplane16[(size_t)b * PLB2 + (size_t)kEa[q] * PX + px] = f2b(sv * hv);
            }
        }
    }
}

// ---------------- GRU out ----------------
__global__ __launch_bounds__(512) void k_gru_out(const unsigned short* __restrict__ rhplane16,
        const float* __restrict__ wxb_t, const float* __restrict__ Uh, const float* __restrict__ zb,
        float* __restrict__ hplane32, unsigned short* __restrict__ hplane16,
        float* __restrict__ assign_t) {
    extern __shared__ float lds[];
    unsigned short* P = (unsigned short*)lds;
    float* red = lds + 8192;
    const int b = blockIdx.x;
    const int k0 = blockIdx.y * 4;
    const int tid = threadIdx.x;
    const int wv = __builtin_amdgcn_readfirstlane(tid >> 6);
    const int lane = tid & 63;
    const int kp = wv >> 2, kiq = wv & 3;

    float preE[2], zvE[2], hpE[2]; bool valE[2]; size_t csE[2], ppE[2];
#pragma unroll
    for (int q = 0; q < 2; ++q) {
        const int o = tid + q * 512;
        const int set = o >> 8, px = o & 255;
        const int kp_o = set >> 1, r = set & 1;
        const int k = k0 + kp_o * 2 + r;
        const int row = px >> 4, col = px & 15;
        valE[q] = (row >= 1 && row <= 14 && col >= 1 && col <= 14);
        csE[q] = ((size_t)b * Kc + k) * Sc + (valE[q] ? (row - 1) * 14 + (col - 1) : 0);
        ppE[q] = (size_t)b * PLB2 + (size_t)k * PX + px;
        preE[q] = 0.f; zvE[q] = 0.f; hpE[q] = 0.f;
        if (valE[q]) {
            preE[q] = wxb_t[csE[q]];
            zvE[q] = zb[csE[q]];
            hpE[q] = hplane32[ppE[q]];
        }
    }
    {
        const float4* src = (const float4*)(rhplane16 + (size_t)b * PLB2);
        float4* dst = (float4*)P;
#pragma unroll
        for (int it = 0; it < 4; ++it) dst[it * 512 + tid] = src[it * 512 + tid];
    }
    __syncthreads();

    const int yp = lane >> 2, xq = (lane & 3) << 2;
    const int rowbase = (yp > 0) ? (yp - 1) : 0;
    const float* uh0 = Uh + (size_t)(k0 + kp * 2) * 576 + kiq * 144;
    float ah[2][4] = {};
    const unsigned short* Pw = P + (size_t)(kiq * 16) * PX + rowbase * 16 + xq;
#pragma unroll 2
    for (int ki = 0; ki < 16; ++ki) {
        const unsigned short* pk = Pw + ki * PX;
#pragma unroll
        for (int dy = 0; dy < 3; ++dy) {
            ushort4 u = *(const ushort4*)(pk + dy * 16);
            float4 m = make_float4(b2f(u.x), b2f(u.y), b2f(u.z), b2f(u.w));
            float e0 = dpp_prev(m.w);
            float e4 = dpp_next(m.x);
#pragma unroll
            for (int r = 0; r < 2; ++r) {
                const float* wh = uh0 + r * 576 + ki * 9 + dy * 3;
                float c0 = wh[0], c1 = wh[1], c2 = wh[2];
                ah[r][0] += c0*e0  + c1*m.x + c2*m.y;
                ah[r][1] += c0*m.x + c1*m.y + c2*m.z;
                ah[r][2] += c0*m.y + c1*m.z + c2*m.w;
                ah[r][3] += c0*m.z + c1*m.w + c2*e4;
            }
        }
    }
    {
        float* rp = red + (size_t)wv * 512 + lane;
#pragma unroll
        for (int r = 0; r < 2; ++r)
#pragma unroll
            for (int jj = 0; jj < 4; ++jj)
                rp[(size_t)(r * 4 + jj) * 64] = ah[r][jj];
    }
    __syncthreads();
#pragma unroll
    for (int q = 0; q < 2; ++q) {
        const int o = tid + q * 512;
        const int set = o >> 8, px = o & 255;
        const int kp_o = set >> 1, r = set & 1;
        const int lane_r = ((px >> 4) << 2) + ((px & 15) >> 2);
        const int v = r * 4 + (px & 3);
        float s0 = 0.f;
#pragma unroll
        for (int kq2 = 0; kq2 < 4; ++kq2)
            s0 += red[(size_t)((kp_o * 4 + kq2) * 8 + v) * 64 + lane_r];
        if (valE[q]) {
            float hh = tanh_f(preE[q] + s0);
            float hn = (1.f - zvE[q]) * hh + zvE[q] * hpE[q];
            hplane32[ppE[q]] = hn;
            hplane16[ppE[q]] = f2b(hn);
            assign_t[csE[q]] = hn;
        }
    }
}

// ---------------- einsum via MFMA (bf16x3), grid (4 cq, 8 tg, 16 b), 512 thr ----------------
__global__ __launch_bounds__(512) void k_einsum(const float* __restrict__ x, const float* __restrict__ assign,
                                                float* __restrict__ part) {
    extern __shared__ float lds[];
    unsigned short* Ah = (unsigned short*)lds;      // [64 k][40 s-pad]
    unsigned short* Al = Ah + 64 * 40;
    unsigned short* Xh = Al + 64 * 40;              // [128 c][40 s-pad]
    unsigned short* Xl = Xh + 128 * 40;
    const int cq = blockIdx.x, tg = blockIdx.y, b = blockIdx.z;
    const int tid = threadIdx.x;
    const int wv = tid >> 6, lane = tid & 63;
    const int lg = lane >> 4, ln = lane & 15;
    const int ka = tid >> 3, ss4 = (tid & 7) * 4;
    const int cx = tid >> 2, ss8 = (tid & 3) * 8;

    f32x4 acc[4];
#pragma unroll
    for (int mt = 0; mt < 4; ++mt) acc[mt] = (f32x4){0.f, 0.f, 0.f, 0.f};

    for (int tt = 0; tt < 2; ++tt) {
        const int t = tg * 2 + tt;
        const int n = b * Tc + t;
        const float* ap = assign + ((size_t)t * Bc + b) * KS;
        const float* xp = x + ((size_t)n * Cc + cq * 128) * Sc;
        for (int sc7 = 0; sc7 < 7; ++sc7) {
            const int s0 = sc7 * 32;
            __syncthreads();
            {
                float4 v = make_float4(0.f, 0.f, 0.f, 0.f);
                if (s0 + ss4 <= 192) v = *(const float4*)(ap + (size_t)ka * Sc + s0 + ss4);
                ushort4 h, l;
                split1(v.x, h.x, l.x); split1(v.y, h.y, l.y);
                split1(v.z, h.z, l.z); split1(v.w, h.w, l.w);
                *(ushort4*)(Ah + ka * 40 + ss4) = h;
                *(ushort4*)(Al + ka * 40 + ss4) = l;
            }
#pragma unroll
            for (int q = 0; q < 2; ++q) {
                const int so = ss8 + q * 4;
                float4 v = make_float4(0.f, 0.f, 0.f, 0.f);
                if (s0 + so <= 192) v = *(const float4*)(xp + (size_t)cx * Sc + s0 + so);
                ushort4 h, l;
                split1(v.x, h.x, l.x); split1(v.y, h.y, l.y);
                split1(v.z, h.z, l.z); split1(v.w, h.w, l.w);
                *(ushort4*)(Xh + cx * 40 + so) = h;
                *(ushort4*)(Xl + cx * 40 + so) = l;
            }
            __syncthreads();
            bf16x8 Bh = *(const bf16x8*)(Xh + (wv * 16 + ln) * 40 + lg * 8);
            bf16x8 Bl = *(const bf16x8*)(Xl + (wv * 16 + ln) * 40 + lg * 8);
#pragma unroll
            for (int mt = 0; mt < 4; ++mt) {
                bf16x8 Af = *(const bf16x8*)(Ah + (mt * 16 + ln) * 40 + lg * 8);
                bf16x8 Alo = *(const bf16x8*)(Al + (mt * 16 + ln) * 40 + lg * 8);
                acc[mt] = __builtin_amdgcn_mfma_f32_16x16x32_bf16(Af, Bh, acc[mt], 0, 0, 0);
                acc[mt] = __builtin_amdgcn_mfma_f32_16x16x32_bf16(Alo, Bh, acc[mt], 0, 0, 0);
                acc[mt] = __builtin_amdgcn_mfma_f32_16x16x32_bf16(Af, Bl, acc[mt], 0, 0, 0);
            }
        }
    }
    const int c = cq * 128 + wv * 16 + ln;
#pragma unroll
    for (int mt = 0; mt < 4; ++mt) {
#pragma unroll
        for (int r = 0; r < 4; ++r) {
            const int k = mt * 16 + lg * 4 + r;
            part[(((size_t)tg * Bc + b) * Kc + k) * Cc + c] = acc[mt][r];
        }
    }
}

// ---------------- reduce: per (b,k): asum + partial-sum + center-subtract + sumsq ----------------
__global__ __launch_bounds__(256) void k_reduce(const float* __restrict__ assign, const float* __restrict__ part,
        const float* __restrict__ centers, float* __restrict__ vlad, float* __restrict__ norm2) {
    __shared__ float redw[4];
    __shared__ float a_s;
    const int blk = blockIdx.x;
    const int b = blk >> 6, k = blk & 63;
    const int tid = threadIdx.x;
    const int wave = tid >> 6, lane = tid & 63;
    const size_t bkoff = ((size_t)b * Kc + k) * Sc;
    float s = 0.f;
    for (int q = tid; q < 784; q += 256) {
        int t = q / 49, s4 = q - t * 49;
        float4 v = *(const float4*)(assign + (size_t)t * BKS + bkoff + s4 * 4);
        s += (v.x + v.y) + (v.z + v.w);
    }
#pragma unroll
    for (int o = 1; o < 64; o <<= 1) s += __shfl_xor(s, o);
    if (lane == 0) redw[wave] = s;
    __syncthreads();
    if (tid == 0) a_s = redw[0] + redw[1] + redw[2] + redw[3];
    __syncthreads();
    const float a = a_s;
    const size_t base = ((size_t)b * Kc + k) * Cc;
    const int c = tid * 2;
    float2 acc2 = make_float2(0.f, 0.f);
#pragma unroll
    for (int g = 0; g < 8; ++g) {
        float2 p = *(const float2*)(part + (size_t)g * GFIN + base + c);
        acc2.x += p.x; acc2.y += p.y;
    }
    float2 cv = *(const float2*)(centers + (size_t)k * Cc + c);
    float v0 = acc2.x - a * cv.x, v1 = acc2.y - a * cv.y;
    *(float2*)(vlad + base + c) = make_float2(v0, v1);
    float ss = v0 * v0 + v1 * v1;
#pragma unroll
    for (int o = 1; o < 64; o <<= 1) ss += __shfl_xor(ss, o);
    __syncthreads();
    if (lane == 0) redw[wave] = ss;
    __syncthreads();
    if (tid == 0) norm2[blk] = redw[0] + redw[1] + redw[2] + redw[3];
}

// ---------------- norms ----------------
__global__ __launch_bounds__(64) void k_norms(const float* __restrict__ norm2, float* __restrict__ scl) {
    const int b = blockIdx.x;
    const int k = threadIdx.x;
    float ss = norm2[b * Kc + k];
    float inv = 1.f / fmaxf(sqrtf(ss), 1e-12f);
    float g = ss * inv * inv;
#pragma unroll
    for (int o = 1; o < 64; o <<= 1) g += __shfl_xor(g, o);
    float gi = 1.f / fmaxf(sqrtf(g), 1e-12f);
    scl[b * Kc + k] = inv * gi;
}

// ---------------- scale ----------------
__global__ __launch_bounds__(256) void k_scale(const float* __restrict__ vlad, const float* __restrict__ scl,
                                               float* __restrict__ out) {
    const int blk = blockIdx.x;           // b*16 + kt
    const int b = blk >> 4, kt = blk & 15;
    const int tid = threadIdx.x;
    const int kk = tid >> 6, lane = tid & 63;
    const int k = kt * 4 + kk;
    const float sv = scl[b * Kc + k];
    const float* vp = vlad + ((size_t)b * Kc + k) * Cc + lane * 8;
    float* op = out + ((size_t)b * Kc + k) * Cc + lane * 8;
    float4 v0 = *(const float4*)vp;
    float4 v1 = *(const float4*)(vp + 4);
    *(float4*)op = make_float4(v0.x * sv, v0.y * sv, v0.z * sv, v0.w * sv);
    *(float4*)(op + 4) = make_float4(v1.x * sv, v1.y * sv, v1.z * sv, v1.w * sv);
}

extern "C" void kernel_launch(void* const* d_in, const int* in_sizes, int n_in,
                              void* d_out, int out_size, void* d_ws, size_t ws_size,
                              hipStream_t stream) {
    (void)in_sizes; (void)n_in; (void)out_size; (void)ws_size;
    const float* x       = (const float*)d_in[0];
    const float* centers = (const float*)d_in[1];
    const float* share_w = (const float*)d_in[2];
    const float* share_b = (const float*)d_in[3];
    const float* Uz      = (const float*)d_in[4];
    const float* Ur      = (const float*)d_in[5];
    const float* Uh      = (const float*)d_in[6];
    float* out = (float*)d_out;
    float* ws  = (float*)d_ws;

    float* part      = ws;
    float* vlad      = ws;
    float* wxb       = ws;
    unsigned short* rhplane16 = (unsigned short*)(ws + (size_t)TBKS);            // [B][64][256] bf16
    unsigned short* hplane16  = (unsigned short*)(ws + (size_t)TBKS + 131072);   // [B][64][256] bf16
    float* assign   = ws + (size_t)PART_N;
    float* zb       = assign + (size_t)TBKS;
    float* hplane32 = zb + (size_t)BKS;              // [B][64][256] fp32
    float* wreg     = hplane32 + (size_t)Bc * PLB2;
    unsigned short* w_hi = (unsigned short*)wreg;
    unsigned short* w_lo = w_hi + (size_t)Kc * Cc;
    float* norm2    = wreg + (size_t)Kc * Cc;
    float* scl      = norm2 + (size_t)Bc * Kc;

    const size_t gates_lds = 65536;                              // 32KB plane + 32KB red
    const size_t outk_lds  = 49152;                              // 32KB plane + 16KB red
    const size_t ein_lds   = (64 * 40 + 128 * 40) * 2 * 2;       // 30.7 KB

    k_prep_w<<<dim3(128), 256, 0, stream>>>(share_w, w_hi, w_lo);
    k_init<<<dim3(256), 256, 0, stream>>>((float4*)hplane32, (float4*)hplane16, (float4*)rhplane16);
    k_conv1x1<<<dim3(784), 512, 0, stream>>>(x, w_hi, w_lo, share_b, wxb,
                                             assign, hplane32, hplane16);
    for (int t = 1; t < Tc; ++t) {
        k_gru_gates<<<dim3(16, 16), 512, gates_lds, stream>>>(hplane16, wxb + (size_t)t * BKS,
                                                              Uz, Ur, zb, rhplane16);
        k_gru_out<<<dim3(16, 16), 512, outk_lds, stream>>>(rhplane16, wxb + (size_t)t * BKS,
                                                           Uh, zb, hplane32, hplane16,
                                                           assign + (size_t)t * BKS);
    }
    k_einsum<<<dim3(4, 8, 16), 512, ein_lds, stream>>>(x, assign, part);
    k_reduce<<<dim3(Bc * Kc), 256, 0, stream>>>(assign, part, centers, vlad, norm2);
    k_norms<<<dim3(Bc), 64, 0, stream>>>(norm2, scl);
    k_scale<<<dim3(256), 256, 0, stream>>>(vlad, scl, out);
}